// Round 7
// baseline (626.796 us; speedup 1.0000x reference)
//
#include <hip/hip_runtime.h>
#include <hip/hip_bf16.h>
#include <math.h>

#define N_PTS 16384
#define KNN 8

#define DT_BF16 1
#define DT_FP32 2

// Workspace layout (identical to the r4 passing build):
//   flag : int          @ 0
//   idx  : int  [N*9]   @ 64        -> 589,824 B
//   x1   : f32  [N*64]  @ 589,888   -> 4,194,304 B
#define WS_FLAG_OFF 0
#define WS_IDX_OFF  64
#define WS_X1_OFF   589888
#define WS_NEEDED   4784192

#define KNN_TGT  16   // targets per block (was 32 in r4)
#define KNN_SCAN 16   // scanners per target (was 8 in r4)

__device__ __forceinline__ float bf2f(__hip_bfloat16 v) { return __bfloat162float(v); }

__device__ __forceinline__ float ldf(const float* p, int i) { return p[i]; }
__device__ __forceinline__ float ldf(const __hip_bfloat16* p, int i) { return bf2f(p[i]); }
__device__ __forceinline__ void stf(float* p, int i, float v) { p[i] = v; }
__device__ __forceinline__ void stf(__hip_bfloat16* p, int i, float v) { p[i] = __float2bfloat16(v); }

__device__ __forceinline__ int clamp_idx(int j) {
    return ((unsigned)j < (unsigned)N_PTS) ? j : 0;
}

// ---------------------------------------------------------------------------
// Kernel 0: dtype sniffer (r4-verbatim).
// ---------------------------------------------------------------------------
__global__ __launch_bounds__(256) void sniff_kernel(const unsigned short* __restrict__ posu,
                                                    int* __restrict__ flag) {
    __shared__ int red[256];
    int local = 0;
    for (int e = threadIdx.x; e < 3 * N_PTS; e += 256) {
        const float v = __uint_as_float(((unsigned)posu[e]) << 16);
        if (!(fabsf(v) <= 64.0f)) local++;
    }
    red[threadIdx.x] = local;
    __syncthreads();
    for (int s = 128; s > 0; s >>= 1) {
        if (threadIdx.x < s) red[threadIdx.x] += red[threadIdx.x + s];
        __syncthreads();
    }
    if (threadIdx.x == 0) flag[0] = (red[0] > 16) ? DT_FP32 : DT_BF16;
}

// ---------------------------------------------------------------------------
// Kernel 1: KNN — r4's proven single-phase insert + shared-tau algorithm,
// regeared from 32x8 to 16x16 (targets x scanners). Grid 512 -> 1024 blocks
// = 4 blocks/CU (r4's counters showed grid-capped 19% occupancy, VALU 61%).
// Total work unchanged; the win is latency hiding. Merge now over 128.
// ---------------------------------------------------------------------------
template <typename T>
__global__ __launch_bounds__(256) void knn_kernel(const T* __restrict__ pos,
                                                  const int* __restrict__ flag, int want,
                                                  int* __restrict__ idx_out) {
    if (flag[0] != want) return;

    const int tid  = threadIdx.x;
    const int tloc = tid >> 4;   // target within block 0..15
    const int part = tid & 15;   // scanner 0..15
    const int i    = blockIdx.x * KNN_TGT + tloc;

    __shared__ float4 spt[256];
    __shared__ float  md[KNN_TGT][129];   // 128 entries + pad
    __shared__ int    mi[KNN_TGT][129];

    const float pix = ldf(pos, 3 * i + 0);
    const float piy = ldf(pos, 3 * i + 1);
    const float piz = ldf(pos, 3 * i + 2);
    const float sqi = fmaf(pix, pix, fmaf(piy, piy, piz * piz));

    float bd[KNN];
    int   bi[KNN];
#pragma unroll
    for (int q = 0; q < KNN; ++q) { bd[q] = INFINITY; bi[q] = 0x7fffffff; }

    for (int base = 0; base < N_PTS; base += 256) {
        {   // stage tile: (-2x, -2y, -2z, |p|^2)
            const int j = base + tid;
            const float x = ldf(pos, 3 * j + 0);
            const float y = ldf(pos, 3 * j + 1);
            const float z = ldf(pos, 3 * j + 2);
            const float sq = fmaf(x, x, fmaf(y, y, z * z));
            spt[tid] = make_float4(-2.0f * x, -2.0f * y, -2.0f * z, sq);
        }
        __syncthreads();

        // shared tau: min of the 16 scanner lanes' bd[7] (xor 1,2,4,8)
        float tau = bd[KNN - 1];
        tau = fminf(tau, __int_as_float(__builtin_amdgcn_ds_swizzle(__float_as_int(tau), 0x041F)));
        tau = fminf(tau, __int_as_float(__builtin_amdgcn_ds_swizzle(__float_as_int(tau), 0x081F)));
        tau = fminf(tau, __int_as_float(__builtin_amdgcn_ds_swizzle(__float_as_int(tau), 0x101F)));
        tau = fminf(tau, __int_as_float(__builtin_amdgcn_ds_swizzle(__float_as_int(tau), 0x201F)));

        int j2 = base + part;
#pragma unroll 4
        for (int m = 0; m < 16; ++m) {
            const float4 c = spt[(m << 4) + part];
            float d = fmaf(c.x, pix, fmaf(c.y, piy, fmaf(c.z, piz, sqi + c.w)));
            d = (j2 == i) ? INFINITY : d;   // exclude self
            if (d < tau) {
                float cd = d; int ci = j2;
#pragma unroll
                for (int q = 0; q < KNN; ++q) {
                    const bool ins = cd < bd[q];
                    const float nd = ins ? cd : bd[q];
                    const int   ni = ins ? ci : bi[q];
                    const float od = ins ? bd[q] : cd;
                    const int   oi = ins ? bi[q] : ci;
                    bd[q] = nd; bi[q] = ni; cd = od; ci = oi;
                }
                tau = fminf(tau, bd[KNN - 1]);   // tighten own view
            }
            j2 += 16;
        }
        __syncthreads();
    }

#pragma unroll
    for (int q = 0; q < KNN; ++q) {
        md[tloc][part * 8 + q] = bd[q];
        mi[tloc][part * 8 + q] = bi[q];
    }
    __syncthreads();

    if (tid < KNN_TGT) {
        const int i2 = blockIdx.x * KNN_TGT + tid;
        unsigned long long used0 = 0ull, used1 = 0ull;
        for (int k = 0; k < KNN; ++k) {
            float bestd = INFINITY; int bestidx = 0x7fffffff; int bestslot = 0;
            for (int s = 0; s < 128; ++s) {
                const bool used = (s < 64) ? ((used0 >> s) & 1ull)
                                           : ((used1 >> (s - 64)) & 1ull);
                if (used) continue;
                const float dd = md[tid][s];
                const int   ii = mi[tid][s];
                if (dd < bestd || (dd == bestd && ii < bestidx)) {
                    bestd = dd; bestidx = ii; bestslot = s;
                }
            }
            if (bestslot < 64) used0 |= 1ull << bestslot;
            else               used1 |= 1ull << (bestslot - 64);
            idx_out[i2 * 9 + k] = clamp_idx(bestidx);
        }
        idx_out[i2 * 9 + 8] = i2;  // self-loop appended, matching reference
    }
}

// ---------------------------------------------------------------------------
// Kernel 2: conv1 (r4-verbatim).
// ---------------------------------------------------------------------------
template <typename T>
__global__ __launch_bounds__(256) void conv1_kernel(const T* __restrict__ pos,
                                                    const int* __restrict__ flag, int want,
                                                    const int* __restrict__ idx,
                                                    const T* __restrict__ W1a,
                                                    const T* __restrict__ b1a,
                                                    const T* __restrict__ W1b,
                                                    const T* __restrict__ b1b,
                                                    float* __restrict__ x1) {
    if (flag[0] != want) return;

    __shared__ float wA[6 * 32];
    __shared__ float bA[32];
    __shared__ float wB[32 * 64];
    __shared__ float bB[64];
    __shared__ float msg[4][9][6];
    __shared__ float h1s[4][9 * 32];

    const int tid = threadIdx.x;
    for (int e = tid; e < 192; e += 256) wA[e] = ldf(W1a, e);
    if (tid < 32) bA[tid] = ldf(b1a, tid);
    for (int e = tid; e < 2048; e += 256) wB[e] = ldf(W1b, e);
    if (tid < 64) bB[tid] = ldf(b1b, tid);

    const int tl   = tid >> 6;
    const int lane = tid & 63;
    const int i    = blockIdx.x * 4 + tl;

    if (lane < 54) {
        const int n = lane / 6, c = lane % 6;
        const int j = clamp_idx(idx[i * 9 + n]);
        float v = ldf(pos, 3 * j + (c % 3));
        if (c >= 3) v -= ldf(pos, 3 * i + (c - 3));
        msg[tl][n][c] = v;
    }
    __syncthreads();

    for (int e = lane; e < 288; e += 64) {
        const int n = e >> 5, k = e & 31;
        float s = bA[k];
#pragma unroll
        for (int c = 0; c < 6; ++c) s += msg[tl][n][c] * wA[c * 32 + k];
        h1s[tl][n * 32 + k] = fmaxf(s, 0.0f);
    }
    __syncthreads();

    float wcol[32];
#pragma unroll
    for (int k = 0; k < 32; ++k) wcol[k] = wB[k * 64 + lane];

    float acc = -INFINITY;
    for (int n = 0; n < 9; ++n) {
        float s = bB[lane];
#pragma unroll
        for (int k = 0; k < 32; ++k) s += h1s[tl][n * 32 + k] * wcol[k];
        acc = fmaxf(acc, s);
    }
    x1[i * 64 + lane] = fmaxf(acc, 0.0f);
}

// ---------------------------------------------------------------------------
// Kernel 3: conv2 + head (r4-verbatim).
// ---------------------------------------------------------------------------
template <typename T>
__global__ __launch_bounds__(256) void conv2_head_kernel(const T* __restrict__ pos,
                                                         const int* __restrict__ flag, int want,
                                                         const int* __restrict__ idx,
                                                         const float* __restrict__ x1,
                                                         const T* __restrict__ W2a,
                                                         const T* __restrict__ b2a,
                                                         const T* __restrict__ W2b,
                                                         const T* __restrict__ b2b,
                                                         const T* __restrict__ Wc,
                                                         const T* __restrict__ bc,
                                                         T* __restrict__ out) {
    if (flag[0] != want) return;

    __shared__ float wAT[64 * 68];
    __shared__ float bA[64];
    __shared__ float wc[640];
    __shared__ float bcs[5];
    __shared__ float msg[4][9 * 68];
    __shared__ float h1s[4][9 * 64];
    __shared__ float row[4][128];
    __shared__ float sv[4][5];

    const int tid  = threadIdx.x;
    const int l    = tid & 127;
    const int half = tid >> 7;

    float wcol[64];
#pragma unroll
    for (int k = 0; k < 64; ++k) wcol[k] = ldf(W2b, k * 128 + l);
    const float bBl = ldf(b2b, l);

    for (int e = tid; e < 4288; e += 256) {
        const int c = e >> 6, k = e & 63;
        wAT[k * 68 + c] = ldf(W2a, e);
    }
    if (tid < 64) wAT[tid * 68 + 67] = 0.0f;
    if (tid < 64) bA[tid] = ldf(b2a, tid);
    for (int e = tid; e < 640; e += 256) wc[e] = ldf(Wc, e);
    if (tid < 5) bcs[tid] = ldf(bc, tid);

    const int tl   = tid >> 6;
    const int lane = tid & 63;
    const int i    = blockIdx.x * 4 + tl;

    for (int e = lane; e < 603; e += 64) {
        const int n = e / 67, c = e % 67;
        const int j = clamp_idx(idx[i * 9 + n]);
        float v;
        if (c < 64) v = x1[j * 64 + c];
        else        v = ldf(pos, 3 * j + (c - 64)) - ldf(pos, 3 * i + (c - 64));
        msg[tl][n * 68 + c] = v;
    }
    if (lane < 9) msg[tl][lane * 68 + 67] = 0.0f;
    __syncthreads();

    {
        float h[9];
#pragma unroll
        for (int n = 0; n < 9; ++n) h[n] = bA[lane];
        for (int c = 0; c < 68; c += 4) {
            const float4 w = *(const float4*)&wAT[lane * 68 + c];
#pragma unroll
            for (int n = 0; n < 9; ++n) {
                const float4 mv = *(const float4*)&msg[tl][n * 68 + c];
                h[n] = fmaf(mv.x, w.x, h[n]);
                h[n] = fmaf(mv.y, w.y, h[n]);
                h[n] = fmaf(mv.z, w.z, h[n]);
                h[n] = fmaf(mv.w, w.w, h[n]);
            }
        }
#pragma unroll
        for (int n = 0; n < 9; ++n) h1s[tl][n * 64 + lane] = fmaxf(h[n], 0.0f);
    }
    __syncthreads();

#pragma unroll
    for (int tt = 0; tt < 2; ++tt) {
        const int tgt = half * 2 + tt;
        float acc = -INFINITY;
        for (int n = 0; n < 9; ++n) {
            float s = bBl;
            for (int k = 0; k < 64; k += 4) {
                const float4 hv = *(const float4*)&h1s[tgt][n * 64 + k];
                s = fmaf(hv.x, wcol[k + 0], s);
                s = fmaf(hv.y, wcol[k + 1], s);
                s = fmaf(hv.z, wcol[k + 2], s);
                s = fmaf(hv.w, wcol[k + 3], s);
            }
            acc = fmaxf(acc, s);
        }
        row[tgt][l] = fmaxf(acc, 0.0f);
    }
    __syncthreads();

    if (tid < 20) {
        const int tgt = tid / 5, o = tid % 5;
        float s = bcs[o];
        for (int k = 0; k < 128; ++k) s += row[tgt][k] * wc[k * 5 + o];
        sv[tgt][o] = s;
    }
    __syncthreads();
    if (tid < 20) {
        const int tgt = tid / 5, o = tid % 5;
        float m = sv[tgt][0];
#pragma unroll
        for (int q = 1; q < 5; ++q) m = fmaxf(m, sv[tgt][q]);
        float sum = 0.0f;
#pragma unroll
        for (int q = 0; q < 5; ++q) sum += expf(sv[tgt][q] - m);
        const float lse = m + logf(sum);
        stf(out, (blockIdx.x * 4 + tgt) * 5 + o, sv[tgt][o] - lse);
    }
}

// ---------------------------------------------------------------------------
extern "C" void kernel_launch(void* const* d_in, const int* in_sizes, int n_in,
                              void* d_out, int out_size, void* d_ws, size_t ws_size,
                              hipStream_t stream) {
    if (ws_size < (size_t)WS_NEEDED) return;

    char* ws = (char*)d_ws;
    int*   flag = (int*)(ws + WS_FLAG_OFF);
    int*   idx  = (int*)(ws + WS_IDX_OFF);
    float* x1   = (float*)(ws + WS_X1_OFF);

    sniff_kernel<<<1, 256, 0, stream>>>((const unsigned short*)d_in[0], flag);

    {
        typedef __hip_bfloat16 T;
        const T* pos = (const T*)d_in[0];
        knn_kernel<T><<<N_PTS / KNN_TGT, 256, 0, stream>>>(pos, flag, DT_BF16, idx);
        conv1_kernel<T><<<N_PTS / 4, 256, 0, stream>>>(pos, flag, DT_BF16, idx,
            (const T*)d_in[1], (const T*)d_in[2], (const T*)d_in[3], (const T*)d_in[4], x1);
        conv2_head_kernel<T><<<N_PTS / 4, 256, 0, stream>>>(pos, flag, DT_BF16, idx, x1,
            (const T*)d_in[5], (const T*)d_in[6], (const T*)d_in[7], (const T*)d_in[8],
            (const T*)d_in[9], (const T*)d_in[10], (T*)d_out);
    }
    {
        typedef float T;
        const T* pos = (const T*)d_in[0];
        knn_kernel<T><<<N_PTS / KNN_TGT, 256, 0, stream>>>(pos, flag, DT_FP32, idx);
        conv1_kernel<T><<<N_PTS / 4, 256, 0, stream>>>(pos, flag, DT_FP32, idx,
            (const T*)d_in[1], (const T*)d_in[2], (const T*)d_in[3], (const T*)d_in[4], x1);
        conv2_head_kernel<T><<<N_PTS / 4, 256, 0, stream>>>(pos, flag, DT_FP32, idx, x1,
            (const T*)d_in[5], (const T*)d_in[6], (const T*)d_in[7], (const T*)d_in[8],
            (const T*)d_in[9], (const T*)d_in[10], (T*)d_out);
    }
}

// Round 9
// 603.469 us; speedup vs baseline: 1.0387x; 1.0387x over previous
//
#include <hip/hip_runtime.h>
#include <hip/hip_bf16.h>
#include <math.h>

#define N_PTS 16384
#define KNN 8

#define DT_BF16 1
#define DT_FP32 2

// Workspace layout (identical to the r4/r7 passing builds):
//   flag : int          @ 0
//   idx  : int  [N*9]   @ 64        -> 589,824 B
//   x1   : f32  [N*64]  @ 589,888   -> 4,194,304 B
#define WS_FLAG_OFF 0
#define WS_IDX_OFF  64
#define WS_X1_OFF   589888
#define WS_NEEDED   4784192

__device__ __forceinline__ float bf2f(__hip_bfloat16 v) { return __bfloat162float(v); }

__device__ __forceinline__ float ldf(const float* p, int i) { return p[i]; }
__device__ __forceinline__ float ldf(const __hip_bfloat16* p, int i) { return bf2f(p[i]); }
__device__ __forceinline__ void stf(float* p, int i, float v) { p[i] = v; }
__device__ __forceinline__ void stf(__hip_bfloat16* p, int i, float v) { p[i] = __float2bfloat16(v); }

__device__ __forceinline__ int clamp_idx(int j) {
    return ((unsigned)j < (unsigned)N_PTS) ? j : 0;
}

// ds_swizzle pattern must be an immediate -> template parameter (r8 compile fix)
template <int PAT>
__device__ __forceinline__ float swz_min(float t) {
    return fminf(t, __int_as_float(__builtin_amdgcn_ds_swizzle(__float_as_int(t), PAT)));
}

// ---------------------------------------------------------------------------
// Kernel 0: dtype sniffer. LOAD-BEARING: r5/r6 (no sniffer, hard-bf16) NaN'd;
// every sniffer build passed. Input dtype evidently varies across runs.
// ---------------------------------------------------------------------------
__global__ __launch_bounds__(256) void sniff_kernel(const unsigned short* __restrict__ posu,
                                                    int* __restrict__ flag) {
    __shared__ int red[256];
    int local = 0;
    for (int e = threadIdx.x; e < 3 * N_PTS; e += 256) {
        const float v = __uint_as_float(((unsigned)posu[e]) << 16);
        if (!(fabsf(v) <= 64.0f)) local++;
    }
    red[threadIdx.x] = local;
    __syncthreads();
    for (int s = 128; s > 0; s >>= 1) {
        if (threadIdx.x < s) red[threadIdx.x] += red[threadIdx.x + s];
        __syncthreads();
    }
    if (threadIdx.x == 0) flag[0] = (red[0] > 16) ? DT_FP32 : DT_BF16;
}

// ---------------------------------------------------------------------------
// Kernel 1: KNN — r4-proven 32 targets x 8 scanners (grid 512; r7's 16x16
// did 1.75x more insert work: per-lane thresholds train on shorter streams).
// New: tau resync across the 8 scanner lanes every 8 candidates (3 swizzles)
// -> tighter tau -> wave-level insert-trigger rate ~75% -> ~35%.
// Drop rule stays exact: tau = some lane's bd[7] means 8 kept entries <= tau.
// ---------------------------------------------------------------------------
template <typename T>
__global__ __launch_bounds__(256) void knn_kernel(const T* __restrict__ pos,
                                                  const int* __restrict__ flag, int want,
                                                  int* __restrict__ idx_out) {
    if (flag[0] != want) return;

    const int tid  = threadIdx.x;
    const int tloc = tid >> 3;   // target within block 0..31
    const int part = tid & 7;    // scanner 0..7 (8 consecutive lanes/target)
    const int i    = blockIdx.x * 32 + tloc;

    __shared__ float4 spt[256];
    __shared__ float  md[32][65];
    __shared__ int    mi[32][65];

    const float pix = ldf(pos, 3 * i + 0);
    const float piy = ldf(pos, 3 * i + 1);
    const float piz = ldf(pos, 3 * i + 2);
    const float sqi = fmaf(pix, pix, fmaf(piy, piy, piz * piz));

    float bd[KNN];
    int   bi[KNN];
#pragma unroll
    for (int q = 0; q < KNN; ++q) { bd[q] = INFINITY; bi[q] = 0x7fffffff; }

    for (int base = 0; base < N_PTS; base += 256) {
        {   // stage tile: (-2x, -2y, -2z, |p|^2)
            const int j = base + tid;
            const float x = ldf(pos, 3 * j + 0);
            const float y = ldf(pos, 3 * j + 1);
            const float z = ldf(pos, 3 * j + 2);
            const float sq = fmaf(x, x, fmaf(y, y, z * z));
            spt[tid] = make_float4(-2.0f * x, -2.0f * y, -2.0f * z, sq);
        }
        __syncthreads();

        int j2 = base + part;
        for (int mm = 0; mm < 4; ++mm) {
            // resync: tau = min over the target's 8 scanner lanes of bd[7]
            float tau = bd[KNN - 1];
            tau = swz_min<0x041F>(tau);   // xor 1
            tau = swz_min<0x081F>(tau);   // xor 2
            tau = swz_min<0x101F>(tau);   // xor 4

#pragma unroll
            for (int m = 0; m < 8; ++m) {
                const float4 c = spt[((mm * 8 + m) << 3) + part];
                float d = fmaf(c.x, pix, fmaf(c.y, piy, fmaf(c.z, piz, sqi + c.w)));
                d = (j2 == i) ? INFINITY : d;   // exclude self
                if (d < tau) {
                    float cd = d; int ci = j2;
#pragma unroll
                    for (int q = 0; q < KNN; ++q) {
                        const bool ins = cd < bd[q];
                        const float nd = ins ? cd : bd[q];
                        const int   ni = ins ? ci : bi[q];
                        const float od = ins ? bd[q] : cd;
                        const int   oi = ins ? bi[q] : ci;
                        bd[q] = nd; bi[q] = ni; cd = od; ci = oi;
                    }
                    tau = fminf(tau, bd[KNN - 1]);
                }
                j2 += 8;
            }
        }
        __syncthreads();
    }

#pragma unroll
    for (int q = 0; q < KNN; ++q) {
        md[tloc][part * 8 + q] = bd[q];
        mi[tloc][part * 8 + q] = bi[q];
    }
    __syncthreads();

    if (tid < 32) {
        const int i2 = blockIdx.x * 32 + tid;
        unsigned long long used = 0ull;
        for (int k = 0; k < KNN; ++k) {
            float bestd = INFINITY; int bestidx = 0x7fffffff; int bestslot = 0;
            for (int s = 0; s < 64; ++s) {
                if ((used >> s) & 1ull) continue;
                const float dd = md[tid][s];
                const int   ii = mi[tid][s];
                if (dd < bestd || (dd == bestd && ii < bestidx)) {
                    bestd = dd; bestidx = ii; bestslot = s;
                }
            }
            used |= 1ull << bestslot;
            idx_out[i2 * 9 + k] = clamp_idx(bestidx);
        }
        idx_out[i2 * 9 + 8] = i2;  // self-loop appended, matching reference
    }
}

// ---------------------------------------------------------------------------
// Kernel 2: conv1 (r4/r7-verbatim).
// ---------------------------------------------------------------------------
template <typename T>
__global__ __launch_bounds__(256) void conv1_kernel(const T* __restrict__ pos,
                                                    const int* __restrict__ flag, int want,
                                                    const int* __restrict__ idx,
                                                    const T* __restrict__ W1a,
                                                    const T* __restrict__ b1a,
                                                    const T* __restrict__ W1b,
                                                    const T* __restrict__ b1b,
                                                    float* __restrict__ x1) {
    if (flag[0] != want) return;

    __shared__ float wA[6 * 32];
    __shared__ float bA[32];
    __shared__ float wB[32 * 64];
    __shared__ float bB[64];
    __shared__ float msg[4][9][6];
    __shared__ float h1s[4][9 * 32];

    const int tid = threadIdx.x;
    for (int e = tid; e < 192; e += 256) wA[e] = ldf(W1a, e);
    if (tid < 32) bA[tid] = ldf(b1a, tid);
    for (int e = tid; e < 2048; e += 256) wB[e] = ldf(W1b, e);
    if (tid < 64) bB[tid] = ldf(b1b, tid);

    const int tl   = tid >> 6;
    const int lane = tid & 63;
    const int i    = blockIdx.x * 4 + tl;

    if (lane < 54) {
        const int n = lane / 6, c = lane % 6;
        const int j = clamp_idx(idx[i * 9 + n]);
        float v = ldf(pos, 3 * j + (c % 3));
        if (c >= 3) v -= ldf(pos, 3 * i + (c - 3));
        msg[tl][n][c] = v;
    }
    __syncthreads();

    for (int e = lane; e < 288; e += 64) {
        const int n = e >> 5, k = e & 31;
        float s = bA[k];
#pragma unroll
        for (int c = 0; c < 6; ++c) s += msg[tl][n][c] * wA[c * 32 + k];
        h1s[tl][n * 32 + k] = fmaxf(s, 0.0f);
    }
    __syncthreads();

    float wcol[32];
#pragma unroll
    for (int k = 0; k < 32; ++k) wcol[k] = wB[k * 64 + lane];

    float acc = -INFINITY;
    for (int n = 0; n < 9; ++n) {
        float s = bB[lane];
#pragma unroll
        for (int k = 0; k < 32; ++k) s += h1s[tl][n * 32 + k] * wcol[k];
        acc = fmaxf(acc, s);
    }
    x1[i * 64 + lane] = fmaxf(acc, 0.0f);
}

// ---------------------------------------------------------------------------
// Kernel 3: conv2 + head v3. Weights fully in registers (wa[68] per lane
// from coalesced global; wcol[64] as before). No wAT LDS staging (was 8-way
// bank-conflicted on read AND write). msg reads are wave-uniform broadcast
// ds_read_b128 (conflict-free). LDS 41 -> ~24 KB.
// ---------------------------------------------------------------------------
template <typename T>
__global__ __launch_bounds__(256) void conv2_head_kernel(const T* __restrict__ pos,
                                                         const int* __restrict__ flag, int want,
                                                         const int* __restrict__ idx,
                                                         const float* __restrict__ x1,
                                                         const T* __restrict__ W2a,
                                                         const T* __restrict__ b2a,
                                                         const T* __restrict__ W2b,
                                                         const T* __restrict__ b2b,
                                                         const T* __restrict__ Wc,
                                                         const T* __restrict__ bc,
                                                         T* __restrict__ out) {
    if (flag[0] != want) return;

    __shared__ float wc[640];
    __shared__ float bcs[5];
    __shared__ float msg[4][9 * 68];   // [tgt][n*68+c], pad zeroed
    __shared__ float h1s[4][9 * 64];
    __shared__ float row[4][128];
    __shared__ float sv[4][5];

    const int tid  = threadIdx.x;
    const int l    = tid & 127;
    const int half = tid >> 7;
    const int tl   = tid >> 6;
    const int lane = tid & 63;
    const int i    = blockIdx.x * 4 + tl;

    // W2a column for output channel `lane` -> registers (coalesced, L2-hot)
    float wa[68];
#pragma unroll
    for (int c = 0; c < 67; ++c) wa[c] = ldf(W2a, c * 64 + lane);
    wa[67] = 0.0f;
    const float bAl = ldf(b2a, lane);

    // W2b column for output channel `l` -> registers
    float wcol[64];
#pragma unroll
    for (int k = 0; k < 64; ++k) wcol[k] = ldf(W2b, k * 128 + l);
    const float bBl = ldf(b2b, l);

    for (int e = tid; e < 640; e += 256) wc[e] = ldf(Wc, e);
    if (tid < 5) bcs[tid] = ldf(bc, tid);

    // msg stage (+ zero pad)
    for (int e = lane; e < 603; e += 64) {
        const int n = e / 67, c = e % 67;
        const int j = clamp_idx(idx[i * 9 + n]);
        float v;
        if (c < 64) v = x1[j * 64 + c];
        else        v = ldf(pos, 3 * j + (c - 64)) - ldf(pos, 3 * i + (c - 64));
        msg[tl][n * 68 + c] = v;
    }
    if (lane < 9) msg[tl][lane * 68 + 67] = 0.0f;
    __syncthreads();

    // h1: thread = (target tl, channel lane); msg float4 reads are
    // wave-uniform broadcasts, weights from registers.
    {
        float h[9];
#pragma unroll
        for (int n = 0; n < 9; ++n) h[n] = bAl;
#pragma unroll
        for (int c = 0; c < 68; c += 4) {
#pragma unroll
            for (int n = 0; n < 9; ++n) {
                const float4 mv = *(const float4*)&msg[tl][n * 68 + c];
                h[n] = fmaf(mv.x, wa[c + 0], h[n]);
                h[n] = fmaf(mv.y, wa[c + 1], h[n]);
                h[n] = fmaf(mv.z, wa[c + 2], h[n]);
                h[n] = fmaf(mv.w, wa[c + 3], h[n]);
            }
        }
#pragma unroll
        for (int n = 0; n < 9; ++n) h1s[tl][n * 64 + lane] = fmaxf(h[n], 0.0f);
    }
    __syncthreads();

    // wB phase: thread (half, l) does 2 targets; h1s reads are broadcasts
#pragma unroll
    for (int tt = 0; tt < 2; ++tt) {
        const int tgt = half * 2 + tt;
        float acc = -INFINITY;
        for (int n = 0; n < 9; ++n) {
            float s = bBl;
#pragma unroll
            for (int k = 0; k < 64; k += 4) {
                const float4 hv = *(const float4*)&h1s[tgt][n * 64 + k];
                s = fmaf(hv.x, wcol[k + 0], s);
                s = fmaf(hv.y, wcol[k + 1], s);
                s = fmaf(hv.z, wcol[k + 2], s);
                s = fmaf(hv.w, wcol[k + 3], s);
            }
            acc = fmaxf(acc, s);
        }
        row[tgt][l] = fmaxf(acc, 0.0f);
    }
    __syncthreads();

    // head + log_softmax
    if (tid < 20) {
        const int tgt = tid / 5, o = tid % 5;
        float s = bcs[o];
        for (int k = 0; k < 128; ++k) s += row[tgt][k] * wc[k * 5 + o];
        sv[tgt][o] = s;
    }
    __syncthreads();
    if (tid < 20) {
        const int tgt = tid / 5, o = tid % 5;
        float m = sv[tgt][0];
#pragma unroll
        for (int q = 1; q < 5; ++q) m = fmaxf(m, sv[tgt][q]);
        float sum = 0.0f;
#pragma unroll
        for (int q = 0; q < 5; ++q) sum += expf(sv[tgt][q] - m);
        const float lse = m + logf(sum);
        stf(out, (blockIdx.x * 4 + tgt) * 5 + o, sv[tgt][o] - lse);
    }
}

// ---------------------------------------------------------------------------
extern "C" void kernel_launch(void* const* d_in, const int* in_sizes, int n_in,
                              void* d_out, int out_size, void* d_ws, size_t ws_size,
                              hipStream_t stream) {
    if (ws_size < (size_t)WS_NEEDED) return;

    char* ws = (char*)d_ws;
    int*   flag = (int*)(ws + WS_FLAG_OFF);
    int*   idx  = (int*)(ws + WS_IDX_OFF);
    float* x1   = (float*)(ws + WS_X1_OFF);

    sniff_kernel<<<1, 256, 0, stream>>>((const unsigned short*)d_in[0], flag);

    {
        typedef __hip_bfloat16 T;
        const T* pos = (const T*)d_in[0];
        knn_kernel<T><<<N_PTS / 32, 256, 0, stream>>>(pos, flag, DT_BF16, idx);
        conv1_kernel<T><<<N_PTS / 4, 256, 0, stream>>>(pos, flag, DT_BF16, idx,
            (const T*)d_in[1], (const T*)d_in[2], (const T*)d_in[3], (const T*)d_in[4], x1);
        conv2_head_kernel<T><<<N_PTS / 4, 256, 0, stream>>>(pos, flag, DT_BF16, idx, x1,
            (const T*)d_in[5], (const T*)d_in[6], (const T*)d_in[7], (const T*)d_in[8],
            (const T*)d_in[9], (const T*)d_in[10], (T*)d_out);
    }
    {
        typedef float T;
        const T* pos = (const T*)d_in[0];
        knn_kernel<T><<<N_PTS / 32, 256, 0, stream>>>(pos, flag, DT_FP32, idx);
        conv1_kernel<T><<<N_PTS / 4, 256, 0, stream>>>(pos, flag, DT_FP32, idx,
            (const T*)d_in[1], (const T*)d_in[2], (const T*)d_in[3], (const T*)d_in[4], x1);
        conv2_head_kernel<T><<<N_PTS / 4, 256, 0, stream>>>(pos, flag, DT_FP32, idx, x1,
            (const T*)d_in[5], (const T*)d_in[6], (const T*)d_in[7], (const T*)d_in[8],
            (const T*)d_in[9], (const T*)d_in[10], (T*)d_out);
    }
}